// Round 2
// baseline (468.975 us; speedup 1.0000x reference)
//
#include <hip/hip_runtime.h>
#include <stdint.h>

#define N_TOK 196
#define DIM   128
#define HEADS 4
#define HD    32
#define NWIN  64
#define NQT   13      // 208 / 16 query tiles
#define NKT   14      // 224 / 16 key tiles
#define SCALE 0.17677669529663687f

typedef __bf16 bf16x8 __attribute__((ext_vector_type(8)));
typedef float  f32x4  __attribute__((ext_vector_type(4)));

__device__ __forceinline__ unsigned short f2bf(float f) {
  union { float f; unsigned u; } c; c.f = f;
  return (unsigned short)((c.u + 0x7FFFu + ((c.u >> 16) & 1u)) >> 16);
}
__device__ __forceinline__ unsigned pack2(float a, float b) {
  return (unsigned)f2bf(a) | ((unsigned)f2bf(b) << 16);
}

// ---------------------------------------------------------------------------
// Kernel A: prep — pos-bias MLP table (729x4), bf16-transposed weights.
// ---------------------------------------------------------------------------
__global__ void prep_kernel(
    const float* __restrict__ qkv_w, const float* __restrict__ proj_w,
    const float* __restrict__ biases,
    const float* __restrict__ pos_proj_w, const float* __restrict__ pos_proj_b,
    const float* __restrict__ ln1_w, const float* __restrict__ ln1_b,
    const float* __restrict__ fc1_w, const float* __restrict__ fc1_b,
    const float* __restrict__ ln2_w, const float* __restrict__ ln2_b,
    const float* __restrict__ fc2_w, const float* __restrict__ fc2_b,
    const float* __restrict__ ln3_w, const float* __restrict__ ln3_b,
    const float* __restrict__ fc3_w, const float* __restrict__ fc3_b,
    unsigned short* __restrict__ wqkv_t, unsigned short* __restrict__ wproj_t,
    float* __restrict__ ptab)
{
  const int tid = threadIdx.x, blk = blockIdx.x;
  if (blk < 3) {
    int r = blk * 256 + tid;
    if (r < 729) {
      float v[8], t[8];
      float b0 = biases[2*r], b1 = biases[2*r+1];
      for (int j = 0; j < 8; ++j)
        v[j] = b0 * pos_proj_w[j] + b1 * pos_proj_w[8+j] + pos_proj_b[j];
      const float* lws[3] = {ln1_w, ln2_w, ln3_w};
      const float* lbs[3] = {ln1_b, ln2_b, ln3_b};
      const float* fws[3] = {fc1_w, fc2_w, fc3_w};
      const float* fbs[3] = {fc1_b, fc2_b, fc3_b};
      for (int L = 0; L < 3; ++L) {
        float mu = 0.f;  for (int j=0;j<8;++j) mu += v[j];  mu *= 0.125f;
        float var = 0.f; for (int j=0;j<8;++j){ float d=v[j]-mu; var+=d*d; } var *= 0.125f;
        float rs = rsqrtf(var + 1e-5f);
        for (int j=0;j<8;++j){ float u=(v[j]-mu)*rs*lws[L][j]+lbs[L][j]; t[j]=fmaxf(u,0.f); }
        int nout = (L==2) ? 4 : 8;
        for (int o=0;o<nout;++o){ float s=fbs[L][o]; for (int j=0;j<8;++j) s += t[j]*fws[L][j*nout+o]; v[o]=s; }
      }
      for (int hh=0; hh<4; ++hh) ptab[r*4+hh] = v[hh];
    }
  } else if (blk < 7) {
    for (int i = (blk-3)*256 + tid; i < 384*128; i += 1024) {
      int col = i >> 7, k = i & 127;
      wqkv_t[i] = f2bf(qkv_w[k*384 + col]);
    }
  } else {
    for (int i = tid; i < 128*128; i += 256) {
      int col = i >> 7, k = i & 127;
      wproj_t[i] = f2bf(proj_w[k*128 + col]);
    }
  }
}

// ---------------------------------------------------------------------------
// Kernel A2: expand gathered bias table to bias_exp[h][q*196+k]
// ---------------------------------------------------------------------------
__global__ void bias_expand_kernel(const int* __restrict__ rel_idx,
                                   const float* __restrict__ ptab,
                                   float* __restrict__ bias_exp)
{
  int i = blockIdx.x * 256 + threadIdx.x;
  if (i < N_TOK*N_TOK) {
    int idx = rel_idx[i];
    #pragma unroll
    for (int hh = 0; hh < 4; ++hh)
      bias_exp[hh*N_TOK*N_TOK + i] = ptab[idx*4 + hh];
  }
}

// ---------------------------------------------------------------------------
// Kernel B: fused attention per (b, h). Writes PRE-projection output to d_out.
// LDS (ushorts): xs[112][136]=15232 | qs[208][40]=8320 | ks[224][40]=8960 |
//                vt[32][232]=7424   -> total 39936 us = 79872 B (2 blocks/CU)
// ps[4][16][224] (P strips) overlaps xs after staging is done.
// ---------------------------------------------------------------------------
#define XS_LD  136
#define QS_LD  40
#define VT_LD  232
#define QS_OFF 15232
#define KS_OFF 23552
#define VT_OFF 32512
#define LDS_US 39936

__launch_bounds__(256, 2)
__global__ void attn_kernel(const float* __restrict__ x,
                            const float* __restrict__ mask,
                            const float* __restrict__ qkv_b,
                            const unsigned short* __restrict__ wqkv_t,
                            const float* __restrict__ bias_exp,
                            float* __restrict__ out)
{
  __shared__ unsigned short lds[LDS_US];
  unsigned short* xs = lds;
  unsigned short* qs = lds + QS_OFF;
  unsigned short* ks = lds + KS_OFF;
  unsigned short* vt = lds + VT_OFF;

  const int tid  = threadIdx.x;
  const int wave = tid >> 6, lane = tid & 63, lr = lane & 15, lg = lane >> 4;
  const int bh = blockIdx.x;
  const int b  = bh >> 2, h = bh & 3;

  // zero FULL q/k/vt regions (24704 ushorts = 12352 uints) so pad rows of K
  // and pad token-columns of V^T are 0.0 (0 x 0 = 0; garbage would be NaN).
  for (int i = tid; i < 12352; i += 256) ((unsigned*)(lds + QS_OFF))[i] = 0u;

  const float* xb = x + (size_t)b * (N_TOK*DIM);

  // stage rows [grow0, grow0+nrows) of x into xs as bf16 (zero past row 195)
  auto stage = [&](int grow0, int nrows) {
    for (int i = tid; i < nrows*32; i += 256) {
      int lrow = i >> 5, c4 = i & 31;
      int grow = grow0 + lrow;
      uint2 val;
      if (grow < N_TOK) {
        float4 v = ((const float4*)xb)[grow*32 + c4];
        val = make_uint2(pack2(v.x, v.y), pack2(v.z, v.w));
      } else val = make_uint2(0u, 0u);
      ((uint2*)xs)[lrow*34 + c4] = val;
    }
  };

  // compute qkv tiles rt in [rtbase, rtbase + nt/6), x rows offset by grow0
  auto qkv_tiles = [&](int nt, int rtbase, int grow0) {
    for (int t = wave; t < nt; t += 4) {
      int rt = rtbase + t / 6, ct = t % 6;
      int sec = ct >> 1;                  // 0=q 1=k 2=v
      int c32 = (ct & 1) * 16 + lr;       // col within head (0..31)
      int gcol = sec * 128 + h * 32 + c32;
      const unsigned short* wcol = wqkv_t + gcol * 128;
      int arow = rt*16 - grow0 + lr;
      f32x4 acc = {0.f,0.f,0.f,0.f};
      #pragma unroll
      for (int kc = 0; kc < 4; ++kc) {
        int k0 = kc*32 + lg*8;
        bf16x8 a = *(const bf16x8*)(xs + arow*XS_LD + k0);
        bf16x8 w = *(const bf16x8*)(wcol + k0);
        acc = __builtin_amdgcn_mfma_f32_16x16x32_bf16(a, w, acc, 0, 0, 0);
      }
      float bias = qkv_b[gcol];
      #pragma unroll
      for (int r = 0; r < 4; ++r) {
        int row = rt*16 + lg*4 + r;
        float val = acc[r] + bias;
        if (sec == 0)      qs[row*QS_LD + c32] = f2bf(val * SCALE);
        else if (sec == 1) ks[row*QS_LD + c32] = f2bf(val);
        else               vt[c32*VT_LD + row] = f2bf(val);
      }
    }
  };

  stage(0, 112);
  __syncthreads();
  qkv_tiles(42, 0, 0);          // rt 0..6 (rows 0..111)
  __syncthreads();
  stage(112, 96);
  __syncthreads();
  qkv_tiles(36, 7, 112);        // rt 7..12 (rows 112..207)
  __syncthreads();

  // ---- attention per query-tile strip (one wave owns qt = wave, wave+4, ...)
  const float* bexp = bias_exp + h * (N_TOK*N_TOK);
  const float* msk  = mask + (size_t)(b & (NWIN-1)) * (N_TOK*N_TOK);
  unsigned short* psw = lds + wave * (16*224);   // overlaps dead xs region

  for (int qt = wave; qt < NQT; qt += 4) {
    bf16x8 aq = *(const bf16x8*)(qs + (qt*16 + lr)*QS_LD + lg*8);
    f32x4 s[NKT];
    #pragma unroll
    for (int kt = 0; kt < NKT; ++kt) {
      bf16x8 bk = *(const bf16x8*)(ks + (kt*16 + lr)*QS_LD + lg*8);
      f32x4 z = {0.f,0.f,0.f,0.f};
      s[kt] = __builtin_amdgcn_mfma_f32_16x16x32_bf16(aq, bk, z, 0, 0, 0);
    }
    // bias + mask, pad cols -> -inf
    #pragma unroll
    for (int r = 0; r < 4; ++r) {
      int row = qt*16 + lg*4 + r;
      int rr = (row < N_TOK) ? row : 0;      // clamp pad rows (results unused)
      const float* be = bexp + rr*N_TOK;
      const float* me = msk  + rr*N_TOK;
      #pragma unroll
      for (int kt = 0; kt < NKT; ++kt) {
        int c = kt*16 + lr;
        if (c < N_TOK) s[kt][r] += be[c] + me[c];
        else           s[kt][r] = -1e30f;
      }
    }
    // softmax (rows live in 16-lane groups; normalization deferred)
    float linv[4];
    #pragma unroll
    for (int r = 0; r < 4; ++r) {
      float m = s[0][r];
      #pragma unroll
      for (int kt = 1; kt < NKT; ++kt) m = fmaxf(m, s[kt][r]);
      #pragma unroll
      for (int off = 1; off < 16; off <<= 1) m = fmaxf(m, __shfl_xor(m, off));
      float ssum = 0.f;
      #pragma unroll
      for (int kt = 0; kt < NKT; ++kt) {
        float p = __expf(s[kt][r] - m);
        s[kt][r] = p; ssum += p;
      }
      #pragma unroll
      for (int off = 1; off < 16; off <<= 1) ssum += __shfl_xor(ssum, off);
      linv[r] = 1.f / ssum;
    }
    // P strip -> LDS (bf16, unnormalized)
    #pragma unroll
    for (int r = 0; r < 4; ++r) {
      int prow = lg*4 + r;
      #pragma unroll
      for (int kt = 0; kt < NKT; ++kt)
        psw[prow*224 + kt*16 + lr] = f2bf(s[kt][r]);
    }
    asm volatile("s_waitcnt lgkmcnt(0)" ::: "memory");
    // PV
    #pragma unroll
    for (int c2 = 0; c2 < 2; ++c2) {
      f32x4 o = {0.f,0.f,0.f,0.f};
      #pragma unroll
      for (int kc = 0; kc < 7; ++kc) {
        bf16x8 ap = *(const bf16x8*)(psw + lr*224 + kc*32 + lg*8);
        bf16x8 bv = *(const bf16x8*)(vt + (c2*16 + lr)*VT_LD + kc*32 + lg*8);
        o = __builtin_amdgcn_mfma_f32_16x16x32_bf16(ap, bv, o, 0, 0, 0);
      }
      #pragma unroll
      for (int r = 0; r < 4; ++r) {
        int row = qt*16 + lg*4 + r;
        if (row < N_TOK)
          out[((size_t)b*N_TOK + row)*DIM + h*HD + c2*16 + lr] = o[r] * linv[r];
      }
    }
  }
}

// ---------------------------------------------------------------------------
// Kernel C: in-place projection on d_out: out = out @ proj_w + proj_b.
// Each block stages its own 64 rows before overwriting them -> race-free.
// ---------------------------------------------------------------------------
__launch_bounds__(256, 4)
__global__ void proj_kernel(float* __restrict__ out,
                            const unsigned short* __restrict__ wproj_t,
                            const float* __restrict__ proj_b)
{
  __shared__ unsigned short aos[64*136];
  const int tid = threadIdx.x;
  const int wave = tid >> 6, lane = tid & 63, lr = lane & 15, lg = lane >> 4;
  const size_t row0 = (size_t)blockIdx.x * 64;
  const float* src = out + row0*DIM;
  for (int i = tid; i < 64*32; i += 256) {
    int lrow = i >> 5, c4 = i & 31;
    float4 v = ((const float4*)src)[i];
    ((uint2*)aos)[lrow*34 + c4] = make_uint2(pack2(v.x, v.y), pack2(v.z, v.w));
  }
  __syncthreads();
  const int rt = wave;
  for (int ct = 0; ct < 8; ++ct) {
    f32x4 acc = {0.f,0.f,0.f,0.f};
    #pragma unroll
    for (int kc = 0; kc < 4; ++kc) {
      int k0 = kc*32 + lg*8;
      bf16x8 a = *(const bf16x8*)(aos + (rt*16 + lr)*136 + k0);
      bf16x8 w = *(const bf16x8*)(wproj_t + (ct*16 + lr)*128 + k0);
      acc = __builtin_amdgcn_mfma_f32_16x16x32_bf16(a, w, acc, 0, 0, 0);
    }
    float bias = proj_b[ct*16 + lr];
    #pragma unroll
    for (int r = 0; r < 4; ++r) {
      size_t grow = row0 + rt*16 + lg*4 + r;
      out[grow*DIM + ct*16 + lr] = acc[r] + bias;
    }
  }
}

// ---------------------------------------------------------------------------
extern "C" void kernel_launch(void* const* d_in, const int* in_sizes, int n_in,
                              void* d_out, int out_size, void* d_ws, size_t ws_size,
                              hipStream_t stream)
{
  const float* x          = (const float*)d_in[0];
  const float* mask       = (const float*)d_in[1];
  const float* qkv_w      = (const float*)d_in[2];
  const float* qkv_b      = (const float*)d_in[3];
  const float* proj_w     = (const float*)d_in[4];
  const float* proj_b     = (const float*)d_in[5];
  const float* pos_proj_w = (const float*)d_in[6];
  const float* pos_proj_b = (const float*)d_in[7];
  const float* ln1_w = (const float*)d_in[8];
  const float* ln1_b = (const float*)d_in[9];
  const float* fc1_w = (const float*)d_in[10];
  const float* fc1_b = (const float*)d_in[11];
  const float* ln2_w = (const float*)d_in[12];
  const float* ln2_b = (const float*)d_in[13];
  const float* fc2_w = (const float*)d_in[14];
  const float* fc2_b = (const float*)d_in[15];
  const float* ln3_w = (const float*)d_in[16];
  const float* ln3_b = (const float*)d_in[17];
  const float* fc3_w = (const float*)d_in[18];
  const float* fc3_b = (const float*)d_in[19];
  const float* biases = (const float*)d_in[20];
  const int*   rel_idx = (const int*)d_in[21];

  // ws layout (total ~762 KB)
  char* ws = (char*)d_ws;
  unsigned short* wqkv_t  = (unsigned short*)(ws);            //  98304 B
  unsigned short* wproj_t = (unsigned short*)(ws + 98304);    //  32768 B
  float*          ptab    = (float*)(ws + 131072);            //  11664 B
  float*          bias_exp= (float*)(ws + 147456);            // 614656 B
  float* out = (float*)d_out;

  prep_kernel<<<8, 256, 0, stream>>>(qkv_w, proj_w, biases, pos_proj_w, pos_proj_b,
      ln1_w, ln1_b, fc1_w, fc1_b, ln2_w, ln2_b, fc2_w, fc2_b,
      ln3_w, ln3_b, fc3_w, fc3_b, wqkv_t, wproj_t, ptab);
  bias_expand_kernel<<<(N_TOK*N_TOK + 255)/256, 256, 0, stream>>>(rel_idx, ptab, bias_exp);
  attn_kernel<<<1024*HEADS, 256, 0, stream>>>(x, mask, qkv_b, wqkv_t, bias_exp, out);
  proj_kernel<<<(1024*N_TOK)/64, 256, 0, stream>>>(out, wproj_t, proj_b);
}